// Round 10
// baseline (1422.594 us; speedup 1.0000x reference)
//
#include <hip/hip_runtime.h>
#include <math.h>

#define TT   100
#define BSZ  2048
#define NCH  4
#define CT   (TT/NCH)        /* 25 steps per chunk */
#define CR   (CT*BSZ)        /* 51200 (t,b) rows per chunk */
#define DR   ((TT+1)*BSZ)
#define NG   624             /* gi width: 3 gates x 208 */
#define GO   208             /* per-gate stride */
#define WR   640             /* whhb rows: 40 tiles (39 real + 1 zero pad) */
#define EPSV 1e-4f

typedef short bfrag __attribute__((ext_vector_type(8)));  /* 8 bf16 (4 VGPR) */
typedef float facc  __attribute__((ext_vector_type(4)));  /* 4 f32 acc */

static __device__ __forceinline__ short f2b(float x){
  union { float f; unsigned u; } c; c.f = x;
  unsigned r = (c.u + 0x7FFFu + ((c.u >> 16) & 1u)) >> 16;   /* RNE */
  return (short)r;
}
static __device__ __forceinline__ float b2f(short s){
  union { unsigned u; float f; } c; c.u = ((unsigned)(unsigned short)s) << 16;
  return c.f;
}
static __device__ __forceinline__ facc mfma16(bfrag a, bfrag b, facc c){
  return __builtin_amdgcn_mfma_f32_16x16x32_bf16(a, b, c, 0, 0, 0);
}
static __device__ __forceinline__ float sigm(float x){ return 1.f/(1.f+__expf(-x)); }
static __device__ __forceinline__ float tanh_f(float x){
  x = fminf(fmaxf(x, -15.f), 15.f);
  float e = __expf(2.f*x);
  return (e-1.f)/(e+1.f);
}
/* LDS-only barrier: no vmcnt drain (all cross-wave deps are LDS) */
static __device__ __forceinline__ void bar_lgkm(){
  asm volatile("s_waitcnt lgkmcnt(0)\n\ts_barrier" ::: "memory");
}
/* park a loop-invariant fragment in the AGPR file (unified RF; MFMA reads B from AGPR) */
static __device__ __forceinline__ void park(bfrag& f){
  asm volatile("" : "+a"(f));
}

/* ---------------- one-kernel prep: all weight conversions (job = blockIdx.y) ---------------- */
__global__ __launch_bounds__(256) void k_prep(
    const float* __restrict__ ae_w2, const float* __restrict__ lce_w2,
    const float* __restrict__ dec_w1, const float* __restrict__ cov_w1,
    const float* __restrict__ dec_w2, const float* __restrict__ cov_w2,
    const float* __restrict__ wih, const float* __restrict__ whh,
    const float* __restrict__ se_w2, const float* __restrict__ ce_w2,
    const float* __restrict__ ae_b2, const float* __restrict__ lce_b2,
    const float* __restrict__ dec_b1, const float* __restrict__ cov_b1,
    const float* __restrict__ dec_b2, const float* __restrict__ cov_b2,
    const float* __restrict__ bhh,
    const float* __restrict__ ae_w1, const float* __restrict__ ae_b1,
    const float* __restrict__ lce_w1, const float* __restrict__ lce_b1,
    short* __restrict__ aew2b, short* __restrict__ lcew2b,
    short* __restrict__ decw1b, short* __restrict__ covw1b,
    short* __restrict__ decw2b, short* __restrict__ covw2b,
    short* __restrict__ wihab, short* __restrict__ wihlb, short* __restrict__ whhb,
    float* __restrict__ sew2T, float* __restrict__ cew2T, float* __restrict__ wihcT,
    float* __restrict__ aeb2p, float* __restrict__ lceb2p,
    float* __restrict__ decb1p, float* __restrict__ covb1p,
    float* __restrict__ decb2p, float* __restrict__ covb2p,
    float* __restrict__ bhhp,
    short* __restrict__ aw1b, short* __restrict__ lw1b,
    float* __restrict__ aeb1p, float* __restrict__ lceb1p){
  int job = blockIdx.y;
  int idx = blockIdx.x*256 + threadIdx.x;
  if (job < 4){                                   /* 208x224 <- 200x200 */
    if (idx >= 208*224) return;
    const float* s = (job==0)?ae_w2:(job==1)?lce_w2:(job==2)?dec_w1:cov_w1;
    short* d = (job==0)?aew2b:(job==1)?lcew2b:(job==2)?decw1b:covw1b;
    int n = idx / 224, k = idx - n*224;
    d[idx] = f2b((n < 200 && k < 200) ? s[n*200 + k] : 0.f);
  } else if (job < 6){                            /* 16x224 <- 12x200 */
    if (idx >= 16*224) return;
    const float* s = (job==4)?dec_w2:cov_w2;
    short* d = (job==4)?decw2b:covw2b;
    int n = idx / 224, k = idx - n*224;
    d[idx] = f2b((n < 12 && k < 200) ? s[n*200 + k] : 0.f);
  } else if (job < 8){                            /* wih gate-layout 624x224, GO=208 */
    if (idx >= NG*224) return;
    int colOff = (job==6) ? 200 : 400;
    short* d = (job==6)?wihab:wihlb;
    int n = idx / 224, k = idx - n*224;
    int gate = n / GO, o = n - gate*GO;
    d[idx] = f2b((o < 200 && k < 200) ? wih[(size_t)(gate*200+o)*600 + colOff + k] : 0.f);
  } else if (job == 8){                           /* whh gate-layout 640x224 (40 tiles) */
    if (idx >= WR*224) return;
    int n = idx / 224, k = idx - n*224;
    int gate = n / GO, o = n - gate*GO;         /* n>=624 -> gate==3 -> zero pad */
    float v = (gate < 3 && o < 200 && k < 200) ? whh[(size_t)(gate*200+o)*200 + k] : 0.f;
    whhb[idx] = f2b(v);
  } else if (job < 11){                           /* fp32 transpose 200x200 */
    if (idx >= 200*200) return;
    const float* s = (job==9)?se_w2:ce_w2;
    float* d = (job==9)?sew2T:cew2T;
    int k = idx / 200, n = idx - k*200;
    d[idx] = s[n*200 + k];
  } else if (job == 11){                          /* wihcT: [200][600] */
    if (idx >= 200*600) return;
    int k = idx / 600, n = idx - k*600;
    wihcT[idx] = wih[(size_t)n*600 + k];
  } else if (job == 12){                          /* all bias pads */
    if (idx < 208)       aeb2p[idx]      = (idx < 200) ? ae_b2[idx] : 0.f;
    else if (idx < 416)  lceb2p[idx-208] = (idx-208 < 200) ? lce_b2[idx-208] : 0.f;
    else if (idx < 624)  decb1p[idx-416] = (idx-416 < 200) ? dec_b1[idx-416] : 0.f;
    else if (idx < 832)  covb1p[idx-624] = (idx-624 < 200) ? cov_b1[idx-624] : 0.f;
    else if (idx < 848)  decb2p[idx-832] = (idx-832 < 12) ? dec_b2[idx-832] : 0.f;
    else if (idx < 864)  covb2p[idx-848] = (idx-848 < 12) ? cov_b2[idx-848] : 0.f;
    else if (idx < 864+WR){
      int n = idx - 864, gate = n / GO, o = n - gate*GO;
      bhhp[n] = (gate < 3 && o < 200) ? bhh[gate*200 + o] : 0.f;
    }
  } else {                                        /* L1 weights as MFMA B-tiles [208][32] */
    if (idx < 208*32){
      int n = idx >> 5, k = idx & 31;
      aw1b[idx] = f2b((n < 200 && k < 4) ? ae_w1[n*4 + k] : 0.f);
      lw1b[idx] = f2b((n < 200 && k < 6) ? lce_w1[n*6 + k] : 0.f);
    } else if (idx < 208*32 + 208){
      int n = idx - 208*32;
      aeb1p[n]  = (n < 200) ? ae_b1[n] : 0.f;
      lceb1p[n] = (n < 200) ? lce_b1[n] : 0.f;
    }
  }
}

/* zero pad cols [200,224) of hidbuf rows [BSZ, BSZ+CR) and hcar rows [0,BSZ) */
__global__ __launch_bounds__(256) void k_zero(short* __restrict__ hidb, float* __restrict__ hcar){
  int idx = blockIdx.x*256 + threadIdx.x;
  if (idx < CR*24){
    int row = idx / 24, k = 200 + (idx - row*24);
    hidb[((size_t)BSZ + row)*224 + k] = 0;
  } else if (idx < CR*24 + BSZ*24){
    int j = idx - CR*24;
    int row = j / 24, k = 200 + (j - row*24);
    hcar[(size_t)row*224 + k] = 0.f;
  }
}

/* ---------------- small two-layer MLP over BS rows (VALU fp32) ---------------- */
__global__ __launch_bounds__(256) void k_mlp2(const float* __restrict__ x, int Kin,
    const float* __restrict__ w1, const float* __restrict__ b1,
    const float* __restrict__ w2T, const float* __restrict__ b2,
    int act_tanh,
    float* __restrict__ outf, int outf_stride,
    short* __restrict__ outb){
  int row = blockIdx.x, t = threadIdx.x;
  __shared__ float xr[16];
  __shared__ float h1[200];
  if (t < Kin) xr[t] = x[(size_t)row*Kin + t];
  __syncthreads();
  if (t < 200){
    float a = b1[t];
    #pragma unroll 4
    for (int i = 0; i < Kin; ++i) a += xr[i] * w1[t*Kin + i];
    h1[t] = fmaxf(a, 0.f);
  }
  __syncthreads();
  if (t < 224){
    float v = 0.f;
    if (t < 200){
      float a = b2[t];
      #pragma unroll 4
      for (int k = 0; k < 200; ++k) a += h1[k] * w2T[k*200 + t];
      v = act_tanh ? tanh_f(a) : fmaxf(a, 0.f);
    }
    if (t < outf_stride) outf[(size_t)row*outf_stride + t] = v;
    if (outb) outb[(size_t)row*224 + t] = f2b(v);
  }
}

/* gi_ctx[b][n624] = bih + ctx_embed @ wih_ctx^T  (gate-aligned GO=208) */
__global__ __launch_bounds__(256) void k_gictx(const float* __restrict__ ctxe,
    const float* __restrict__ wT, const float* __restrict__ bih, float* __restrict__ gic){
  int b = blockIdx.x, t = threadIdx.x;
  __shared__ float cr[200];
  if (t < 200) cr[t] = ctxe[(size_t)b*200 + t];
  __syncthreads();
  for (int n = t; n < NG; n += 256){
    int gate = n / GO, o = n - gate*GO;
    float a = 0.f;
    if (o < 200){
      int sc = gate*200 + o;
      a = bih[sc];
      #pragma unroll 4
      for (int k = 0; k < 200; ++k) a += cr[k] * wT[k*600 + sc];
    }
    gic[(size_t)b*NG + n] = a;
  }
}

/* ---------------- fused: L1(MFMA) -> L2(MFMA) -> gi GEMM (n-stationary, AGPR-parked B) ---- */
__global__ __launch_bounds__(512, 2) void k_fuse(
    const float* __restrict__ u, const float* __restrict__ lc,
    const short* __restrict__ aw1b, const float* __restrict__ aeb1p,
    const short* __restrict__ lw1b, const float* __restrict__ lceb1p,
    const short* __restrict__ aw2b, const float* __restrict__ ab2p,
    const short* __restrict__ lw2b, const float* __restrict__ lb2p,
    const short* __restrict__ wihab, const short* __restrict__ wihlb,
    short* __restrict__ gibuf, int rowBase){
  __shared__ short t1[2][128][232];
  __shared__ short uB[128][40];    /* bf16, cols 0-3 data, rest zero (k-pad) */
  __shared__ short lcB[128][40];   /* cols 0-5 data */
  int tid = threadIdx.x;
  int r0 = blockIdx.x * 128;
  /* stage 0: stage inputs as bf16 A-tiles; zero t1 pad cols */
  for (int e = tid; e < 128*40; e += 512){
    int row = e / 40, k = e - row*40;
    size_t rg = (size_t)rowBase + r0 + row;
    uB[row][k]  = (k < 4) ? f2b(u[rg*4 + k])  : 0;
    lcB[row][k] = (k < 6) ? f2b(lc[rg*6 + k]) : 0;
  }
  for (int e = tid; e < 2*128*16; e += 512){
    int c = e & 15, row = (e >> 4) & 127, ch = e >> 11;
    t1[ch][row][208 + c] = 0;
  }
  bar_lgkm();
  int w = tid >> 6, lane = tid & 63, lm = lane & 15, lq = lane >> 4;
  int ch = w >> 2;                 /* 0..1 */
  int mb = (w & 3) * 2;            /* m-tile pair: mb, mb+1 (of 8) */
  /* stage 1: L1 via MFMA (K=32 padded) */
  {
    const short (*src)[40] = ch ? lcB : uB;
    const short* w1b = ch ? lw1b : aw1b;
    const float* b1p = ch ? lceb1p : aeb1p;
    bfrag Au0 = *reinterpret_cast<const bfrag*>(&src[mb*16 + lm][lq*8]);
    bfrag Au1 = *reinterpret_cast<const bfrag*>(&src[(mb+1)*16 + lm][lq*8]);
    for (int nt = 0; nt < 13; ++nt){
      int col = nt*16 + lm;
      bfrag Bf = *reinterpret_cast<const bfrag*>(&w1b[col*32 + lq*8]);
      facc z = {0.f,0.f,0.f,0.f};
      facc a0 = mfma16(Au0, Bf, z);
      facc a1 = mfma16(Au1, Bf, z);
      float bias = b1p[col];
      #pragma unroll
      for (int i = 0; i < 4; ++i){
        t1[ch][mb*16     + lq*4 + i][col] = f2b(fmaxf(a0[i] + bias, 0.f));
        t1[ch][(mb+1)*16 + lq*4 + i][col] = f2b(fmaxf(a1[i] + bias, 0.f));
      }
    }
  }
  bar_lgkm();
  /* stage 2/3: L2 MFMA, B double-buffered; in-place t1 write (own rows only) */
  {
    const short* w2b = ch ? lw2b : aw2b;
    const float* b2p = ch ? lb2p : ab2p;
    bfrag A0[7], A1[7];
    #pragma unroll
    for (int ks = 0; ks < 7; ++ks){
      A0[ks] = *reinterpret_cast<const bfrag*>(&t1[ch][mb*16 + lm][ks*32 + lq*8]);
      A1[ks] = *reinterpret_cast<const bfrag*>(&t1[ch][(mb+1)*16 + lm][ks*32 + lq*8]);
    }
    bfrag Bc[7], Bn[7];
    #pragma unroll
    for (int ks = 0; ks < 7; ++ks)
      Bc[ks] = *reinterpret_cast<const bfrag*>(&w2b[(size_t)lm*224 + ks*32 + lq*8]);
    for (int nt = 0; nt < 13; ++nt){
      int col = nt*16 + lm;
      if (nt < 12){
        int coln = col + 16;
        #pragma unroll
        for (int ks = 0; ks < 7; ++ks)
          Bn[ks] = *reinterpret_cast<const bfrag*>(&w2b[(size_t)coln*224 + ks*32 + lq*8]);
      }
      facc a0 = {0.f,0.f,0.f,0.f}, a1 = {0.f,0.f,0.f,0.f};
      #pragma unroll
      for (int ks = 0; ks < 7; ++ks){
        a0 = mfma16(A0[ks], Bc[ks], a0);
        a1 = mfma16(A1[ks], Bc[ks], a1);
      }
      float bias = b2p[col];
      #pragma unroll
      for (int i = 0; i < 4; ++i){
        t1[ch][mb*16     + lq*4 + i][col] = f2b(fmaxf(a0[i] + bias, 0.f));
        t1[ch][(mb+1)*16 + lq*4 + i][col] = f2b(fmaxf(a1[i] + bias, 0.f));
      }
      #pragma unroll
      for (int ks = 0; ks < 7; ++ks) Bc[ks] = Bn[ks];
    }
  }
  bar_lgkm();
  /* stage 4: gi GEMM, n-stationary; resident B-pair parked in AGPRs across full m-loop */
  {
    int ntBase = w*5;
    int ntCnt  = (w < 7) ? 5 : 4;
    for (int gs = 0; gs < ntCnt; gs += 2){
      int gc = ntCnt - gs; if (gc > 2) gc = 2;   /* wave-uniform */
      bfrag Bres[2][14];
      #pragma unroll
      for (int s = 0; s < 2; ++s) if (s < gc){
        int col = (ntBase + gs + s)*16 + lm;
        #pragma unroll
        for (int ks = 0; ks < 7; ++ks){
          Bres[s][ks]   = *reinterpret_cast<const bfrag*>(&wihab[(size_t)col*224 + ks*32 + lq*8]);
          Bres[s][7+ks] = *reinterpret_cast<const bfrag*>(&wihlb[(size_t)col*224 + ks*32 + lq*8]);
          park(Bres[s][ks]); park(Bres[s][7+ks]);
        }
      }
      for (int m = 0; m < 8; ++m){
        bfrag Af[14];
        #pragma unroll
        for (int ks = 0; ks < 7; ++ks){
          Af[ks]   = *reinterpret_cast<const bfrag*>(&t1[0][m*16 + lm][ks*32 + lq*8]);
          Af[7+ks] = *reinterpret_cast<const bfrag*>(&t1[1][m*16 + lm][ks*32 + lq*8]);
        }
        #pragma unroll
        for (int s = 0; s < 2; ++s) if (s < gc){
          facc a = {0.f,0.f,0.f,0.f};
          #pragma unroll
          for (int kk = 0; kk < 14; ++kk) a = mfma16(Af[kk], Bres[s][kk], a);
          int col = (ntBase + gs + s)*16 + lm;
          #pragma unroll
          for (int i = 0; i < 4; ++i){
            int rl = m*16 + lq*4 + i;
            gibuf[((size_t)r0 + rl)*NG + col] = f2b(a[i]);
          }
        }
      }
    }
  }
}

/* ---------------- GRU scan v5: 256 blocks x 512 thr, 8 rows/block ----------------
   Uniform 40 tiles (5/wave, no guards); W_hh fragments parked in AGPRs (140 regs/wave,
   loaded once). gi prefetched one full step ahead. 2 lgkm barriers/step. */
__global__ __launch_bounds__(512, 2) void k_gru5(
    const short* __restrict__ gib, const float* __restrict__ gic,
    const float* __restrict__ hin,
    const short* __restrict__ whhb, const float* __restrict__ bhhp,
    short* __restrict__ hidb, float* __restrict__ hout){
  __shared__ float ghT[WR][12];      /* [col640][row 0..7], stride 12 dwords */
  __shared__ short hB[2][16][232];
  int tid = threadIdx.x;
  int r0 = blockIdx.x * 8;
  int w = tid >> 6, lane = tid & 63, lm = lane & 15, lq = lane >> 4;
  int nt0 = w*5;
  /* resident W fragments, parked in AGPR file */
  bfrag Bg[5][7];
  float bia[5];
  #pragma unroll
  for (int s = 0; s < 5; ++s){
    int col = (nt0+s)*16 + lm;
    bia[s] = bhhp[col];
    #pragma unroll
    for (int ks = 0; ks < 7; ++ks){
      Bg[s][ks] = *reinterpret_cast<const bfrag*>(&whhb[(size_t)col*224 + ks*32 + lq*8]);
      park(Bg[s][ks]);
    }
  }
  int gj = tid >> 1, grh = tid & 1;
  bool gact = (tid < 416) && (gj < 200);
  float hreg[4], gicv[3][4];
  #pragma unroll
  for (int i = 0; i < 4; ++i){
    hreg[i] = gact ? hin[(size_t)(r0 + grh*4 + i)*224 + gj] : 0.f;
    #pragma unroll
    for (int g = 0; g < 3; ++g)
      gicv[g][i] = gact ? gic[(size_t)(r0 + grh*4 + i)*NG + g*GO + gj] : 0.f;
  }
  for (int e = tid; e < 2*16*232; e += 512) (&hB[0][0][0])[e] = 0;
  __syncthreads();
  for (int e = tid; e < 8*224; e += 512){
    int row = e / 224, k = e - row*224;
    hB[0][row][k] = f2b(hin[(size_t)(r0+row)*224 + k]);
  }
  __syncthreads();
  /* gi double-buffer: preload t=0 */
  float gv[2][3][4];
  {
    const short* gp = gib + ((size_t)(r0 + grh*4))*NG + gj;
    #pragma unroll
    for (int i = 0; i < 4; ++i){
      gv[0][0][i] = gact ? b2f(gp[i*NG        ]) : 0.f;
      gv[0][1][i] = gact ? b2f(gp[i*NG + GO   ]) : 0.f;
      gv[0][2][i] = gact ? b2f(gp[i*NG + 2*GO ]) : 0.f;
    }
  }
  for (int t = 0; t < CT; ++t){
    int cur = t & 1, nxt = cur ^ 1;
    /* MFMA phase: gh = h @ W_hh^T + bhh -> ghT (uniform 5 tiles) */
    bfrag hf[7];
    #pragma unroll
    for (int ks = 0; ks < 7; ++ks)
      hf[ks] = *reinterpret_cast<const bfrag*>(&hB[cur][lm][ks*32 + lq*8]);
    #pragma unroll
    for (int s = 0; s < 5; ++s){
      facc a = {0.f,0.f,0.f,0.f};
      #pragma unroll
      for (int ks = 0; ks < 7; ++ks) a = mfma16(hf[ks], Bg[s][ks], a);
      if (lq < 2){
        int col = (nt0+s)*16 + lm;
        a[0] += bia[s]; a[1] += bia[s]; a[2] += bia[s]; a[3] += bia[s];
        *reinterpret_cast<facc*>(&ghT[col][lq*4]) = a;
      }
    }
    bar_lgkm();
    /* prefetch gi for t+1 (a full step of latency cover) */
    if (t + 1 < CT){
      const short* gp = gib + ((size_t)(t+1)*BSZ + r0 + grh*4)*NG + gj;
      #pragma unroll
      for (int i = 0; i < 4; ++i){
        gv[nxt][0][i] = gact ? b2f(gp[i*NG        ]) : 0.f;
        gv[nxt][1][i] = gact ? b2f(gp[i*NG + GO   ]) : 0.f;
        gv[nxt][2][i] = gact ? b2f(gp[i*NG + 2*GO ]) : 0.f;
      }
    }
    /* gate phase */
    if (gact){
      facc R = *reinterpret_cast<facc*>(&ghT[gj][grh*4]);
      facc Z = *reinterpret_cast<facc*>(&ghT[GO + gj][grh*4]);
      facc N = *reinterpret_cast<facc*>(&ghT[2*GO + gj][grh*4]);
      short* hp = hidb + ((size_t)(t+1)*BSZ + r0 + grh*4)*224 + gj;
      #pragma unroll
      for (int i = 0; i < 4; ++i){
        float r  = sigm(gv[cur][0][i] + gicv[0][i] + R[i]);
        float zz = sigm(gv[cur][1][i] + gicv[1][i] + Z[i]);
        float n  = tanh_f(gv[cur][2][i] + gicv[2][i] + r*N[i]);
        float hn = (1.f - zz)*n + zz*hreg[i];
        hreg[i] = hn;
        short hb = f2b(hn);
        hB[nxt][grh*4 + i][gj] = hb;
        hp[i*224] = hb;
      }
    }
    bar_lgkm();
  }
  if (gact)
    #pragma unroll
    for (int i = 0; i < 4; ++i)
      hout[(size_t)(r0 + grh*4 + i)*224 + gj] = hreg[i];
}

/* ---------------- fused decode + cov heads over one chunk of hiddens ---------------- */
__global__ __launch_bounds__(256) void k_dec(
    const short* __restrict__ hidb, int rowStart, int outBase,
    const short* __restrict__ dw1b, const float* __restrict__ db1p,
    const short* __restrict__ dw2b, const float* __restrict__ db2p,
    const short* __restrict__ cw1b, const float* __restrict__ cb1p,
    const short* __restrict__ cw2b, const float* __restrict__ cb2p,
    float* __restrict__ outMean, float* __restrict__ outStd){
  __shared__ short h1t[64][224];
  int tid = threadIdx.x;
  int r0 = rowStart + blockIdx.x * 64;
  int w = tid >> 6, lane = tid & 63, lm = lane & 15, lq = lane >> 4;
  for (int e = tid; e < 64*16; e += 256)
    h1t[e >> 4][208 + (e & 15)] = 0;
  bfrag hf[4][7];
  #pragma unroll
  for (int m = 0; m < 4; ++m)
    #pragma unroll
    for (int ks = 0; ks < 7; ++ks)
      hf[m][ks] = *reinterpret_cast<const bfrag*>(&hidb[(size_t)(r0 + m*16 + lm)*224 + ks*32 + lq*8]);
  int ntStart = (w == 0) ? 0 : 4 + 3*(w-1);
  int ntCnt   = (w == 0) ? 4 : 3;
  for (int pass = 0; pass < 2; ++pass){
    const short* w1b = pass ? cw1b : dw1b;
    const float* b1p = pass ? cb1p : db1p;
    const short* w2b = pass ? cw2b : dw2b;
    const float* b2p = pass ? cb2p : db2p;
    bar_lgkm();
    for (int nti = 0; nti < ntCnt; ++nti){
      int nt = ntStart + nti;
      int col = nt*16 + lm;
      facc z = {0.f,0.f,0.f,0.f};
      facc acc[4] = {z,z,z,z};
      #pragma unroll
      for (int ks = 0; ks < 7; ++ks){
        bfrag bf = *reinterpret_cast<const bfrag*>(&w1b[(size_t)col*224 + ks*32 + lq*8]);
        #pragma unroll
        for (int m = 0; m < 4; ++m) acc[m] = mfma16(hf[m][ks], bf, acc[m]);
      }
      float bias = b1p[col];
      #pragma unroll
      for (int m = 0; m < 4; ++m)
        #pragma unroll
        for (int i = 0; i < 4; ++i)
          h1t[m*16 + lq*4 + i][col] = f2b(fmaxf(acc[m][i] + bias, 0.f));
    }
    bar_lgkm();
    bfrag a2[7];
    #pragma unroll
    for (int ks = 0; ks < 7; ++ks)
      a2[ks] = *reinterpret_cast<const bfrag*>(&h1t[w*16 + lm][ks*32 + lq*8]);
    facc acc = {0.f,0.f,0.f,0.f};
    #pragma unroll
    for (int ks = 0; ks < 7; ++ks){
      bfrag bf = *reinterpret_cast<const bfrag*>(&w2b[(size_t)lm*224 + ks*32 + lq*8]);
      acc = mfma16(a2[ks], bf, acc);
    }
    if (lm < 12){
      float bias = b2p[lm];
      #pragma unroll
      for (int i = 0; i < 4; ++i){
        size_t rg = (size_t)outBase + r0 + w*16 + lq*4 + i;
        float v = acc[i] + bias;
        if (pass){
          float sp = (v > 15.f) ? v : log1pf(__expf(v));
          outStd[rg*12 + lm] = sqrtf(sp + EPSV);
        } else {
          outMean[rg*12 + lm] = v;
        }
      }
    }
  }
}

extern "C" void kernel_launch(void* const* d_in, const int* in_sizes, int n_in,
                              void* d_out, int out_size, void* d_ws, size_t ws_size,
                              hipStream_t stream){
  (void)in_sizes; (void)n_in; (void)out_size; (void)ws_size;
  const float* x      = (const float*)d_in[0];
  const float* u      = (const float*)d_in[1];
  const float* ctxm   = (const float*)d_in[2];
  const float* lctx   = (const float*)d_in[3];
  const float* se_w1  = (const float*)d_in[4];
  const float* se_b1  = (const float*)d_in[5];
  const float* se_w2  = (const float*)d_in[6];
  const float* se_b2  = (const float*)d_in[7];
  const float* ae_w1  = (const float*)d_in[8];
  const float* ae_b1  = (const float*)d_in[9];
  const float* ae_w2  = (const float*)d_in[10];
  const float* ae_b2  = (const float*)d_in[11];
  const float* ce_w1  = (const float*)d_in[12];
  const float* ce_b1  = (const float*)d_in[13];
  const float* ce_w2  = (const float*)d_in[14];
  const float* ce_b2  = (const float*)d_in[15];
  const float* lce_w1 = (const float*)d_in[16];
  const float* lce_b1 = (const float*)d_in[17];
  const float* lce_w2 = (const float*)d_in[18];
  const float* lce_b2 = (const float*)d_in[19];
  const float* dec_w1 = (const float*)d_in[20];
  const float* dec_b1 = (const float*)d_in[21];
  const float* dec_w2 = (const float*)d_in[22];
  const float* dec_b2 = (const float*)d_in[23];
  const float* wih    = (const float*)d_in[24];
  const float* bih    = (const float*)d_in[25];
  const float* whh    = (const float*)d_in[26];
  const float* bhh    = (const float*)d_in[27];
  const float* cov_w1 = (const float*)d_in[28];
  const float* cov_b1 = (const float*)d_in[29];
  const float* cov_w2 = (const float*)d_in[30];
  const float* cov_b2 = (const float*)d_in[31];

  char* ws = (char*)d_ws;
  size_t off = 0;
  auto alloc = [&](size_t sz) -> char* {
    char* p = ws + off; off = (off + sz + 255) & ~(size_t)255; return p;
  };
  short* aew2b  = (short*)alloc(208*224*2);
  short* lcew2b = (short*)alloc(208*224*2);
  short* decw1b = (short*)alloc(208*224*2);
  short* covw1b = (short*)alloc(208*224*2);
  short* decw2b = (short*)alloc(16*224*2);
  short* covw2b = (short*)alloc(16*224*2);
  short* wihab  = (short*)alloc((size_t)NG*224*2);
  short* wihlb  = (short*)alloc((size_t)NG*224*2);
  short* whhb   = (short*)alloc((size_t)WR*224*2);
  float* sew2T  = (float*)alloc(200*200*4);
  float* cew2T  = (float*)alloc(200*200*4);
  float* wihcT  = (float*)alloc(200*600*4);
  float* aeb2p  = (float*)alloc(208*4);
  float* lceb2p = (float*)alloc(208*4);
  float* decb1p = (float*)alloc(208*4);
  float* covb1p = (float*)alloc(208*4);
  float* decb2p = (float*)alloc(16*4);
  float* covb2p = (float*)alloc(16*4);
  float* bhhp   = (float*)alloc(WR*4);
  short* aw1b   = (short*)alloc(208*32*2);
  short* lw1b   = (short*)alloc(208*32*2);
  float* aeb1p  = (float*)alloc(208*4);
  float* lceb1p = (float*)alloc(208*4);
  float* gic    = (float*)alloc((size_t)BSZ*NG*4);
  float* h0f    = (float*)alloc((size_t)BSZ*224*4);
  float* hcar   = (float*)alloc((size_t)BSZ*224*4);
  float* ctxef  = (float*)alloc((size_t)BSZ*200*4);
  short* hidbuf = (short*)alloc((size_t)(CT+1)*BSZ*224*2);
  short* gibuf  = (short*)alloc((size_t)CR*NG*2);

  float* outMean = (float*)d_out;
  float* outStd  = outMean + (size_t)DR*12;

  /* prep: 14 jobs, x-grid sized for the largest (640x224) */
  k_prep<<<dim3((WR*224 + 255)/256, 14), 256, 0, stream>>>(
      ae_w2, lce_w2, dec_w1, cov_w1, dec_w2, cov_w2, wih, whh, se_w2, ce_w2,
      ae_b2, lce_b2, dec_b1, cov_b1, dec_b2, cov_b2, bhh,
      ae_w1, ae_b1, lce_w1, lce_b1,
      aew2b, lcew2b, decw1b, covw1b, decw2b, covw2b,
      wihab, wihlb, whhb, sew2T, cew2T, wihcT,
      aeb2p, lceb2p, decb1p, covb1p, decb2p, covb2p, bhhp,
      aw1b, lw1b, aeb1p, lceb1p);
  k_zero<<<(CR*24 + BSZ*24 + 255)/256, 256, 0, stream>>>(hidbuf, hcar);

  k_mlp2<<<BSZ, 256, 0, stream>>>(x,    12, se_w1, se_b1, sew2T, se_b2, 1, h0f,   224, hidbuf);
  k_mlp2<<<BSZ, 256, 0, stream>>>(ctxm,  8, ce_w1, ce_b1, cew2T, ce_b2, 0, ctxef, 200, (short*)nullptr);
  k_gictx<<<BSZ, 256, 0, stream>>>(ctxef, wihcT, bih, gic);

  for (int c = 0; c < NCH; ++c){
    k_fuse<<<CR/128, 512, 0, stream>>>(u, lctx, aw1b, aeb1p, lw1b, lceb1p,
                                       aew2b, aeb2p, lcew2b, lceb2p,
                                       wihab, wihlb, gibuf, c*CR);
    k_gru5<<<BSZ/8, 512, 0, stream>>>(gibuf, gic, (c == 0) ? h0f : hcar,
                                      whhb, bhhp, hidbuf, hcar);
    int rowStart = (c == 0) ? 0 : BSZ;
    int nRows    = (c == 0) ? (CT+1)*BSZ : CT*BSZ;
    k_dec<<<nRows/64, 256, 0, stream>>>(hidbuf, rowStart, c*CT*BSZ,
                                        decw1b, decb1p, decw2b, decb2p,
                                        covw1b, covb1p, covw2b, covb2p,
                                        outMean, outStd);
  }
}

// Round 11
// 1109.933 us; speedup vs baseline: 1.2817x; 1.2817x over previous
//
#include <hip/hip_runtime.h>
#include <math.h>

#define TT   100
#define BSZ  2048
#define NCH  4
#define CT   (TT/NCH)        /* 25 steps per chunk */
#define CR   (CT*BSZ)        /* 51200 (t,b) rows per chunk */
#define DR   ((TT+1)*BSZ)
#define NG   624             /* gi width: 3 gates x 208 */
#define GO   208             /* per-gate stride */
#define WR   640             /* whhb rows: 40 tiles (39 real + 1 zero pad) */
#define EPSV 1e-4f

typedef short bfrag __attribute__((ext_vector_type(8)));  /* 8 bf16 (4 VGPR) */
typedef float facc  __attribute__((ext_vector_type(4)));  /* 4 f32 acc */

static __device__ __forceinline__ short f2b(float x){
  union { float f; unsigned u; } c; c.f = x;
  unsigned r = (c.u + 0x7FFFu + ((c.u >> 16) & 1u)) >> 16;   /* RNE */
  return (short)r;
}
static __device__ __forceinline__ float b2f(short s){
  union { unsigned u; float f; } c; c.u = ((unsigned)(unsigned short)s) << 16;
  return c.f;
}
static __device__ __forceinline__ facc mfma16(bfrag a, bfrag b, facc c){
  return __builtin_amdgcn_mfma_f32_16x16x32_bf16(a, b, c, 0, 0, 0);
}
static __device__ __forceinline__ float sigm(float x){ return 1.f/(1.f+__expf(-x)); }
static __device__ __forceinline__ float tanh_f(float x){
  x = fminf(fmaxf(x, -15.f), 15.f);
  float e = __expf(2.f*x);
  return (e-1.f)/(e+1.f);
}
/* LDS-only barrier: no vmcnt drain (all cross-wave deps are LDS) */
static __device__ __forceinline__ void bar_lgkm(){
  asm volatile("s_waitcnt lgkmcnt(0)\n\ts_barrier" ::: "memory");
}
/* opaque VGPR def: makes the loaded fragment non-rematerializable (defeats
   invariant-load remat that keeps sinking W loads into the loop), without the
   AGPR-copy penalty of an "a" constraint. */
static __device__ __forceinline__ void parkv(bfrag& f){
  asm volatile("" : "+v"(f));
}

/* ---------------- one-kernel prep: all weight conversions (job = blockIdx.y) ---------------- */
__global__ __launch_bounds__(256) void k_prep(
    const float* __restrict__ ae_w2, const float* __restrict__ lce_w2,
    const float* __restrict__ dec_w1, const float* __restrict__ cov_w1,
    const float* __restrict__ dec_w2, const float* __restrict__ cov_w2,
    const float* __restrict__ wih, const float* __restrict__ whh,
    const float* __restrict__ se_w2, const float* __restrict__ ce_w2,
    const float* __restrict__ ae_b2, const float* __restrict__ lce_b2,
    const float* __restrict__ dec_b1, const float* __restrict__ cov_b1,
    const float* __restrict__ dec_b2, const float* __restrict__ cov_b2,
    const float* __restrict__ bhh,
    const float* __restrict__ ae_w1, const float* __restrict__ ae_b1,
    const float* __restrict__ lce_w1, const float* __restrict__ lce_b1,
    short* __restrict__ aew2b, short* __restrict__ lcew2b,
    short* __restrict__ decw1b, short* __restrict__ covw1b,
    short* __restrict__ decw2b, short* __restrict__ covw2b,
    short* __restrict__ wihab, short* __restrict__ wihlb, short* __restrict__ whhb,
    float* __restrict__ sew2T, float* __restrict__ cew2T, float* __restrict__ wihcT,
    float* __restrict__ aeb2p, float* __restrict__ lceb2p,
    float* __restrict__ decb1p, float* __restrict__ covb1p,
    float* __restrict__ decb2p, float* __restrict__ covb2p,
    float* __restrict__ bhhp,
    short* __restrict__ aw1b, short* __restrict__ lw1b,
    float* __restrict__ aeb1p, float* __restrict__ lceb1p){
  int job = blockIdx.y;
  int idx = blockIdx.x*256 + threadIdx.x;
  if (job < 4){                                   /* 208x224 <- 200x200 */
    if (idx >= 208*224) return;
    const float* s = (job==0)?ae_w2:(job==1)?lce_w2:(job==2)?dec_w1:cov_w1;
    short* d = (job==0)?aew2b:(job==1)?lcew2b:(job==2)?decw1b:covw1b;
    int n = idx / 224, k = idx - n*224;
    d[idx] = f2b((n < 200 && k < 200) ? s[n*200 + k] : 0.f);
  } else if (job < 6){                            /* 16x224 <- 12x200 */
    if (idx >= 16*224) return;
    const float* s = (job==4)?dec_w2:cov_w2;
    short* d = (job==4)?decw2b:covw2b;
    int n = idx / 224, k = idx - n*224;
    d[idx] = f2b((n < 12 && k < 200) ? s[n*200 + k] : 0.f);
  } else if (job < 8){                            /* wih gate-layout 624x224, GO=208 */
    if (idx >= NG*224) return;
    int colOff = (job==6) ? 200 : 400;
    short* d = (job==6)?wihab:wihlb;
    int n = idx / 224, k = idx - n*224;
    int gate = n / GO, o = n - gate*GO;
    d[idx] = f2b((o < 200 && k < 200) ? wih[(size_t)(gate*200+o)*600 + colOff + k] : 0.f);
  } else if (job == 8){                           /* whh gate-layout 640x224 (40 tiles) */
    if (idx >= WR*224) return;
    int n = idx / 224, k = idx - n*224;
    int gate = n / GO, o = n - gate*GO;         /* n>=624 -> gate==3 -> zero pad */
    float v = (gate < 3 && o < 200 && k < 200) ? whh[(size_t)(gate*200+o)*200 + k] : 0.f;
    whhb[idx] = f2b(v);
  } else if (job < 11){                           /* fp32 transpose 200x200 */
    if (idx >= 200*200) return;
    const float* s = (job==9)?se_w2:ce_w2;
    float* d = (job==9)?sew2T:cew2T;
    int k = idx / 200, n = idx - k*200;
    d[idx] = s[n*200 + k];
  } else if (job == 11){                          /* wihcT: [200][600] */
    if (idx >= 200*600) return;
    int k = idx / 600, n = idx - k*600;
    wihcT[idx] = wih[(size_t)n*600 + k];
  } else if (job == 12){                          /* all bias pads */
    if (idx < 208)       aeb2p[idx]      = (idx < 200) ? ae_b2[idx] : 0.f;
    else if (idx < 416)  lceb2p[idx-208] = (idx-208 < 200) ? lce_b2[idx-208] : 0.f;
    else if (idx < 624)  decb1p[idx-416] = (idx-416 < 200) ? dec_b1[idx-416] : 0.f;
    else if (idx < 832)  covb1p[idx-624] = (idx-624 < 200) ? cov_b1[idx-624] : 0.f;
    else if (idx < 848)  decb2p[idx-832] = (idx-832 < 12) ? dec_b2[idx-832] : 0.f;
    else if (idx < 864)  covb2p[idx-848] = (idx-848 < 12) ? cov_b2[idx-848] : 0.f;
    else if (idx < 864+WR){
      int n = idx - 864, gate = n / GO, o = n - gate*GO;
      bhhp[n] = (gate < 3 && o < 200) ? bhh[gate*200 + o] : 0.f;
    }
  } else {                                        /* L1 weights as MFMA B-tiles [208][32] */
    if (idx < 208*32){
      int n = idx >> 5, k = idx & 31;
      aw1b[idx] = f2b((n < 200 && k < 4) ? ae_w1[n*4 + k] : 0.f);
      lw1b[idx] = f2b((n < 200 && k < 6) ? lce_w1[n*6 + k] : 0.f);
    } else if (idx < 208*32 + 208){
      int n = idx - 208*32;
      aeb1p[n]  = (n < 200) ? ae_b1[n] : 0.f;
      lceb1p[n] = (n < 200) ? lce_b1[n] : 0.f;
    }
  }
}

/* zero pad cols [200,224) of hidbuf rows [BSZ, BSZ+CR) and hcar rows [0,BSZ) */
__global__ __launch_bounds__(256) void k_zero(short* __restrict__ hidb, float* __restrict__ hcar){
  int idx = blockIdx.x*256 + threadIdx.x;
  if (idx < CR*24){
    int row = idx / 24, k = 200 + (idx - row*24);
    hidb[((size_t)BSZ + row)*224 + k] = 0;
  } else if (idx < CR*24 + BSZ*24){
    int j = idx - CR*24;
    int row = j / 24, k = 200 + (j - row*24);
    hcar[(size_t)row*224 + k] = 0.f;
  }
}

/* ---------------- small two-layer MLP over BS rows (VALU fp32) ---------------- */
__global__ __launch_bounds__(256) void k_mlp2(const float* __restrict__ x, int Kin,
    const float* __restrict__ w1, const float* __restrict__ b1,
    const float* __restrict__ w2T, const float* __restrict__ b2,
    int act_tanh,
    float* __restrict__ outf, int outf_stride,
    short* __restrict__ outb){
  int row = blockIdx.x, t = threadIdx.x;
  __shared__ float xr[16];
  __shared__ float h1[200];
  if (t < Kin) xr[t] = x[(size_t)row*Kin + t];
  __syncthreads();
  if (t < 200){
    float a = b1[t];
    #pragma unroll 4
    for (int i = 0; i < Kin; ++i) a += xr[i] * w1[t*Kin + i];
    h1[t] = fmaxf(a, 0.f);
  }
  __syncthreads();
  if (t < 224){
    float v = 0.f;
    if (t < 200){
      float a = b2[t];
      #pragma unroll 4
      for (int k = 0; k < 200; ++k) a += h1[k] * w2T[k*200 + t];
      v = act_tanh ? tanh_f(a) : fmaxf(a, 0.f);
    }
    if (t < outf_stride) outf[(size_t)row*outf_stride + t] = v;
    if (outb) outb[(size_t)row*224 + t] = f2b(v);
  }
}

/* gi_ctx[b][n624] = bih + ctx_embed @ wih_ctx^T  (gate-aligned GO=208) */
__global__ __launch_bounds__(256) void k_gictx(const float* __restrict__ ctxe,
    const float* __restrict__ wT, const float* __restrict__ bih, float* __restrict__ gic){
  int b = blockIdx.x, t = threadIdx.x;
  __shared__ float cr[200];
  if (t < 200) cr[t] = ctxe[(size_t)b*200 + t];
  __syncthreads();
  for (int n = t; n < NG; n += 256){
    int gate = n / GO, o = n - gate*GO;
    float a = 0.f;
    if (o < 200){
      int sc = gate*200 + o;
      a = bih[sc];
      #pragma unroll 4
      for (int k = 0; k < 200; ++k) a += cr[k] * wT[k*600 + sc];
    }
    gic[(size_t)b*NG + n] = a;
  }
}

/* ---------------- fused: L1(MFMA) -> L2(MFMA) -> gi GEMM (n-stationary, VGPR-parked B) ---- */
__global__ __launch_bounds__(512, 2) void k_fuse(
    const float* __restrict__ u, const float* __restrict__ lc,
    const short* __restrict__ aw1b, const float* __restrict__ aeb1p,
    const short* __restrict__ lw1b, const float* __restrict__ lceb1p,
    const short* __restrict__ aw2b, const float* __restrict__ ab2p,
    const short* __restrict__ lw2b, const float* __restrict__ lb2p,
    const short* __restrict__ wihab, const short* __restrict__ wihlb,
    short* __restrict__ gibuf, int rowBase){
  __shared__ short t1[2][128][232];
  __shared__ short uB[128][40];    /* bf16, cols 0-3 data, rest zero (k-pad) */
  __shared__ short lcB[128][40];   /* cols 0-5 data */
  int tid = threadIdx.x;
  int r0 = blockIdx.x * 128;
  /* stage 0: stage inputs as bf16 A-tiles; zero t1 pad cols */
  for (int e = tid; e < 128*40; e += 512){
    int row = e / 40, k = e - row*40;
    size_t rg = (size_t)rowBase + r0 + row;
    uB[row][k]  = (k < 4) ? f2b(u[rg*4 + k])  : 0;
    lcB[row][k] = (k < 6) ? f2b(lc[rg*6 + k]) : 0;
  }
  for (int e = tid; e < 2*128*16; e += 512){
    int c = e & 15, row = (e >> 4) & 127, ch = e >> 11;
    t1[ch][row][208 + c] = 0;
  }
  bar_lgkm();
  int w = tid >> 6, lane = tid & 63, lm = lane & 15, lq = lane >> 4;
  int ch = w >> 2;                 /* 0..1 */
  int mb = (w & 3) * 2;            /* m-tile pair: mb, mb+1 (of 8) */
  /* stage 1: L1 via MFMA (K=32 padded) */
  {
    const short (*src)[40] = ch ? lcB : uB;
    const short* w1b = ch ? lw1b : aw1b;
    const float* b1p = ch ? lceb1p : aeb1p;
    bfrag Au0 = *reinterpret_cast<const bfrag*>(&src[mb*16 + lm][lq*8]);
    bfrag Au1 = *reinterpret_cast<const bfrag*>(&src[(mb+1)*16 + lm][lq*8]);
    for (int nt = 0; nt < 13; ++nt){
      int col = nt*16 + lm;
      bfrag Bf = *reinterpret_cast<const bfrag*>(&w1b[col*32 + lq*8]);
      facc z = {0.f,0.f,0.f,0.f};
      facc a0 = mfma16(Au0, Bf, z);
      facc a1 = mfma16(Au1, Bf, z);
      float bias = b1p[col];
      #pragma unroll
      for (int i = 0; i < 4; ++i){
        t1[ch][mb*16     + lq*4 + i][col] = f2b(fmaxf(a0[i] + bias, 0.f));
        t1[ch][(mb+1)*16 + lq*4 + i][col] = f2b(fmaxf(a1[i] + bias, 0.f));
      }
    }
  }
  bar_lgkm();
  /* stage 2/3: L2 MFMA, B double-buffered; in-place t1 write (own rows only) */
  {
    const short* w2b = ch ? lw2b : aw2b;
    const float* b2p = ch ? lb2p : ab2p;
    bfrag A0[7], A1[7];
    #pragma unroll
    for (int ks = 0; ks < 7; ++ks){
      A0[ks] = *reinterpret_cast<const bfrag*>(&t1[ch][mb*16 + lm][ks*32 + lq*8]);
      A1[ks] = *reinterpret_cast<const bfrag*>(&t1[ch][(mb+1)*16 + lm][ks*32 + lq*8]);
    }
    bfrag Bc[7], Bn[7];
    #pragma unroll
    for (int ks = 0; ks < 7; ++ks)
      Bc[ks] = *reinterpret_cast<const bfrag*>(&w2b[(size_t)lm*224 + ks*32 + lq*8]);
    for (int nt = 0; nt < 13; ++nt){
      int col = nt*16 + lm;
      if (nt < 12){
        int coln = col + 16;
        #pragma unroll
        for (int ks = 0; ks < 7; ++ks)
          Bn[ks] = *reinterpret_cast<const bfrag*>(&w2b[(size_t)coln*224 + ks*32 + lq*8]);
      }
      facc a0 = {0.f,0.f,0.f,0.f}, a1 = {0.f,0.f,0.f,0.f};
      #pragma unroll
      for (int ks = 0; ks < 7; ++ks){
        a0 = mfma16(A0[ks], Bc[ks], a0);
        a1 = mfma16(A1[ks], Bc[ks], a1);
      }
      float bias = b2p[col];
      #pragma unroll
      for (int i = 0; i < 4; ++i){
        t1[ch][mb*16     + lq*4 + i][col] = f2b(fmaxf(a0[i] + bias, 0.f));
        t1[ch][(mb+1)*16 + lq*4 + i][col] = f2b(fmaxf(a1[i] + bias, 0.f));
      }
      #pragma unroll
      for (int ks = 0; ks < 7; ++ks) Bc[ks] = Bn[ks];
    }
  }
  bar_lgkm();
  /* stage 4: gi GEMM, n-stationary; resident B-pair pinned in VGPRs across full m-loop */
  {
    int ntBase = w*5;
    int ntCnt  = (w < 7) ? 5 : 4;
    for (int gs = 0; gs < ntCnt; gs += 2){
      int gc = ntCnt - gs; if (gc > 2) gc = 2;   /* wave-uniform */
      bfrag Bres[2][14];
      #pragma unroll
      for (int s = 0; s < 2; ++s) if (s < gc){
        int col = (ntBase + gs + s)*16 + lm;
        #pragma unroll
        for (int ks = 0; ks < 7; ++ks){
          Bres[s][ks]   = *reinterpret_cast<const bfrag*>(&wihab[(size_t)col*224 + ks*32 + lq*8]);
          Bres[s][7+ks] = *reinterpret_cast<const bfrag*>(&wihlb[(size_t)col*224 + ks*32 + lq*8]);
          parkv(Bres[s][ks]); parkv(Bres[s][7+ks]);
        }
      }
      for (int m = 0; m < 8; ++m){
        bfrag Af[14];
        #pragma unroll
        for (int ks = 0; ks < 7; ++ks){
          Af[ks]   = *reinterpret_cast<const bfrag*>(&t1[0][m*16 + lm][ks*32 + lq*8]);
          Af[7+ks] = *reinterpret_cast<const bfrag*>(&t1[1][m*16 + lm][ks*32 + lq*8]);
        }
        #pragma unroll
        for (int s = 0; s < 2; ++s) if (s < gc){
          facc a = {0.f,0.f,0.f,0.f};
          #pragma unroll
          for (int kk = 0; kk < 14; ++kk) a = mfma16(Af[kk], Bres[s][kk], a);
          int col = (ntBase + gs + s)*16 + lm;
          #pragma unroll
          for (int i = 0; i < 4; ++i){
            int rl = m*16 + lq*4 + i;
            gibuf[((size_t)r0 + rl)*NG + col] = f2b(a[i]);
          }
        }
      }
    }
  }
}

/* ---------------- GRU scan v6: 256 blocks x 512 thr, 8 rows/block ----------------
   Uniform 40 tiles (5/wave, no guards); W_hh fragments pinned in VGPRs via opaque
   asm defs (140 regs/wave, loaded once — defeats invariant-load remat).
   2 lgkm barriers/step. */
__global__ __launch_bounds__(512, 2) void k_gru6(
    const short* __restrict__ gib, const float* __restrict__ gic,
    const float* __restrict__ hin,
    const short* __restrict__ whhb, const float* __restrict__ bhhp,
    short* __restrict__ hidb, float* __restrict__ hout){
  __shared__ float ghT[WR][12];      /* [col640][row 0..7], stride 12 dwords */
  __shared__ short hB[2][16][232];
  int tid = threadIdx.x;
  int r0 = blockIdx.x * 8;
  int w = tid >> 6, lane = tid & 63, lm = lane & 15, lq = lane >> 4;
  int nt0 = w*5;
  /* resident W fragments, pinned in VGPRs */
  bfrag Bg[5][7];
  float bia[5];
  #pragma unroll
  for (int s = 0; s < 5; ++s){
    int col = (nt0+s)*16 + lm;
    bia[s] = bhhp[col];
    #pragma unroll
    for (int ks = 0; ks < 7; ++ks){
      Bg[s][ks] = *reinterpret_cast<const bfrag*>(&whhb[(size_t)col*224 + ks*32 + lq*8]);
      parkv(Bg[s][ks]);
    }
  }
  int gj = tid >> 1, grh = tid & 1;
  bool gact = (tid < 416) && (gj < 200);
  float hreg[4], gicv[3][4];
  #pragma unroll
  for (int i = 0; i < 4; ++i){
    hreg[i] = gact ? hin[(size_t)(r0 + grh*4 + i)*224 + gj] : 0.f;
    #pragma unroll
    for (int g = 0; g < 3; ++g)
      gicv[g][i] = gact ? gic[(size_t)(r0 + grh*4 + i)*NG + g*GO + gj] : 0.f;
  }
  for (int e = tid; e < 2*16*232; e += 512) (&hB[0][0][0])[e] = 0;
  __syncthreads();
  for (int e = tid; e < 8*224; e += 512){
    int row = e / 224, k = e - row*224;
    hB[0][row][k] = f2b(hin[(size_t)(r0+row)*224 + k]);
  }
  __syncthreads();
  for (int t = 0; t < CT; ++t){
    int cur = t & 1, nxt = cur ^ 1;
    /* issue gi loads early (consumed after barrier) */
    float gr[4], gz[4], gn[4];
    const short* gp = gib + ((size_t)t*BSZ + r0 + grh*4)*NG + gj;
    #pragma unroll
    for (int i = 0; i < 4; ++i){
      gr[i] = gact ? b2f(gp[i*NG        ]) + gicv[0][i] : 0.f;
      gz[i] = gact ? b2f(gp[i*NG + GO   ]) + gicv[1][i] : 0.f;
      gn[i] = gact ? b2f(gp[i*NG + 2*GO ]) + gicv[2][i] : 0.f;
    }
    /* MFMA phase: gh = h @ W_hh^T + bhh -> ghT (uniform 5 tiles) */
    bfrag hf[7];
    #pragma unroll
    for (int ks = 0; ks < 7; ++ks)
      hf[ks] = *reinterpret_cast<const bfrag*>(&hB[cur][lm][ks*32 + lq*8]);
    #pragma unroll
    for (int s = 0; s < 5; ++s){
      facc a = {0.f,0.f,0.f,0.f};
      #pragma unroll
      for (int ks = 0; ks < 7; ++ks) a = mfma16(hf[ks], Bg[s][ks], a);
      if (lq < 2){
        int col = (nt0+s)*16 + lm;
        a[0] += bia[s]; a[1] += bia[s]; a[2] += bia[s]; a[3] += bia[s];
        *reinterpret_cast<facc*>(&ghT[col][lq*4]) = a;
      }
    }
    bar_lgkm();
    /* gate phase */
    if (gact){
      facc R = *reinterpret_cast<facc*>(&ghT[gj][grh*4]);
      facc Z = *reinterpret_cast<facc*>(&ghT[GO + gj][grh*4]);
      facc N = *reinterpret_cast<facc*>(&ghT[2*GO + gj][grh*4]);
      short* hp = hidb + ((size_t)(t+1)*BSZ + r0 + grh*4)*224 + gj;
      #pragma unroll
      for (int i = 0; i < 4; ++i){
        float r  = sigm(gr[i] + R[i]);
        float zz = sigm(gz[i] + Z[i]);
        float n  = tanh_f(gn[i] + r*N[i]);
        float hn = (1.f - zz)*n + zz*hreg[i];
        hreg[i] = hn;
        short hb = f2b(hn);
        hB[nxt][grh*4 + i][gj] = hb;
        hp[i*224] = hb;
      }
    }
    bar_lgkm();
  }
  if (gact)
    #pragma unroll
    for (int i = 0; i < 4; ++i)
      hout[(size_t)(r0 + grh*4 + i)*224 + gj] = hreg[i];
}

/* ---------------- fused decode + cov heads over one chunk of hiddens ---------------- */
__global__ __launch_bounds__(256) void k_dec(
    const short* __restrict__ hidb, int rowStart, int outBase,
    const short* __restrict__ dw1b, const float* __restrict__ db1p,
    const short* __restrict__ dw2b, const float* __restrict__ db2p,
    const short* __restrict__ cw1b, const float* __restrict__ cb1p,
    const short* __restrict__ cw2b, const float* __restrict__ cb2p,
    float* __restrict__ outMean, float* __restrict__ outStd){
  __shared__ short h1t[64][224];
  int tid = threadIdx.x;
  int r0 = rowStart + blockIdx.x * 64;
  int w = tid >> 6, lane = tid & 63, lm = lane & 15, lq = lane >> 4;
  for (int e = tid; e < 64*16; e += 256)
    h1t[e >> 4][208 + (e & 15)] = 0;
  bfrag hf[4][7];
  #pragma unroll
  for (int m = 0; m < 4; ++m)
    #pragma unroll
    for (int ks = 0; ks < 7; ++ks)
      hf[m][ks] = *reinterpret_cast<const bfrag*>(&hidb[(size_t)(r0 + m*16 + lm)*224 + ks*32 + lq*8]);
  int ntStart = (w == 0) ? 0 : 4 + 3*(w-1);
  int ntCnt   = (w == 0) ? 4 : 3;
  for (int pass = 0; pass < 2; ++pass){
    const short* w1b = pass ? cw1b : dw1b;
    const float* b1p = pass ? cb1p : db1p;
    const short* w2b = pass ? cw2b : dw2b;
    const float* b2p = pass ? cb2p : db2p;
    bar_lgkm();
    for (int nti = 0; nti < ntCnt; ++nti){
      int nt = ntStart + nti;
      int col = nt*16 + lm;
      facc z = {0.f,0.f,0.f,0.f};
      facc acc[4] = {z,z,z,z};
      #pragma unroll
      for (int ks = 0; ks < 7; ++ks){
        bfrag bf = *reinterpret_cast<const bfrag*>(&w1b[(size_t)col*224 + ks*32 + lq*8]);
        #pragma unroll
        for (int m = 0; m < 4; ++m) acc[m] = mfma16(hf[m][ks], bf, acc[m]);
      }
      float bias = b1p[col];
      #pragma unroll
      for (int m = 0; m < 4; ++m)
        #pragma unroll
        for (int i = 0; i < 4; ++i)
          h1t[m*16 + lq*4 + i][col] = f2b(fmaxf(acc[m][i] + bias, 0.f));
    }
    bar_lgkm();
    bfrag a2[7];
    #pragma unroll
    for (int ks = 0; ks < 7; ++ks)
      a2[ks] = *reinterpret_cast<const bfrag*>(&h1t[w*16 + lm][ks*32 + lq*8]);
    facc acc = {0.f,0.f,0.f,0.f};
    #pragma unroll
    for (int ks = 0; ks < 7; ++ks){
      bfrag bf = *reinterpret_cast<const bfrag*>(&w2b[(size_t)lm*224 + ks*32 + lq*8]);
      acc = mfma16(a2[ks], bf, acc);
    }
    if (lm < 12){
      float bias = b2p[lm];
      #pragma unroll
      for (int i = 0; i < 4; ++i){
        size_t rg = (size_t)outBase + r0 + w*16 + lq*4 + i;
        float v = acc[i] + bias;
        if (pass){
          float sp = (v > 15.f) ? v : log1pf(__expf(v));
          outStd[rg*12 + lm] = sqrtf(sp + EPSV);
        } else {
          outMean[rg*12 + lm] = v;
        }
      }
    }
  }
}

extern "C" void kernel_launch(void* const* d_in, const int* in_sizes, int n_in,
                              void* d_out, int out_size, void* d_ws, size_t ws_size,
                              hipStream_t stream){
  (void)in_sizes; (void)n_in; (void)out_size; (void)ws_size;
  const float* x      = (const float*)d_in[0];
  const float* u      = (const float*)d_in[1];
  const float* ctxm   = (const float*)d_in[2];
  const float* lctx   = (const float*)d_in[3];
  const float* se_w1  = (const float*)d_in[4];
  const float* se_b1  = (const float*)d_in[5];
  const float* se_w2  = (const float*)d_in[6];
  const float* se_b2  = (const float*)d_in[7];
  const float* ae_w1  = (const float*)d_in[8];
  const float* ae_b1  = (const float*)d_in[9];
  const float* ae_w2  = (const float*)d_in[10];
  const float* ae_b2  = (const float*)d_in[11];
  const float* ce_w1  = (const float*)d_in[12];
  const float* ce_b1  = (const float*)d_in[13];
  const float* ce_w2  = (const float*)d_in[14];
  const float* ce_b2  = (const float*)d_in[15];
  const float* lce_w1 = (const float*)d_in[16];
  const float* lce_b1 = (const float*)d_in[17];
  const float* lce_w2 = (const float*)d_in[18];
  const float* lce_b2 = (const float*)d_in[19];
  const float* dec_w1 = (const float*)d_in[20];
  const float* dec_b1 = (const float*)d_in[21];
  const float* dec_w2 = (const float*)d_in[22];
  const float* dec_b2 = (const float*)d_in[23];
  const float* wih    = (const float*)d_in[24];
  const float* bih    = (const float*)d_in[25];
  const float* whh    = (const float*)d_in[26];
  const float* bhh    = (const float*)d_in[27];
  const float* cov_w1 = (const float*)d_in[28];
  const float* cov_b1 = (const float*)d_in[29];
  const float* cov_w2 = (const float*)d_in[30];
  const float* cov_b2 = (const float*)d_in[31];

  char* ws = (char*)d_ws;
  size_t off = 0;
  auto alloc = [&](size_t sz) -> char* {
    char* p = ws + off; off = (off + sz + 255) & ~(size_t)255; return p;
  };
  short* aew2b  = (short*)alloc(208*224*2);
  short* lcew2b = (short*)alloc(208*224*2);
  short* decw1b = (short*)alloc(208*224*2);
  short* covw1b = (short*)alloc(208*224*2);
  short* decw2b = (short*)alloc(16*224*2);
  short* covw2b = (short*)alloc(16*224*2);
  short* wihab  = (short*)alloc((size_t)NG*224*2);
  short* wihlb  = (short*)alloc((size_t)NG*224*2);
  short* whhb   = (short*)alloc((size_t)WR*224*2);
  float* sew2T  = (float*)alloc(200*200*4);
  float* cew2T  = (float*)alloc(200*200*4);
  float* wihcT  = (float*)alloc(200*600*4);
  float* aeb2p  = (float*)alloc(208*4);
  float* lceb2p = (float*)alloc(208*4);
  float* decb1p = (float*)alloc(208*4);
  float* covb1p = (float*)alloc(208*4);
  float* decb2p = (float*)alloc(16*4);
  float* covb2p = (float*)alloc(16*4);
  float* bhhp   = (float*)alloc(WR*4);
  short* aw1b   = (short*)alloc(208*32*2);
  short* lw1b   = (short*)alloc(208*32*2);
  float* aeb1p  = (float*)alloc(208*4);
  float* lceb1p = (float*)alloc(208*4);
  float* gic    = (float*)alloc((size_t)BSZ*NG*4);
  float* h0f    = (float*)alloc((size_t)BSZ*224*4);
  float* hcar   = (float*)alloc((size_t)BSZ*224*4);
  float* ctxef  = (float*)alloc((size_t)BSZ*200*4);
  short* hidbuf = (short*)alloc((size_t)(CT+1)*BSZ*224*2);
  short* gibuf  = (short*)alloc((size_t)CR*NG*2);

  float* outMean = (float*)d_out;
  float* outStd  = outMean + (size_t)DR*12;

  /* prep: 14 jobs, x-grid sized for the largest (640x224) */
  k_prep<<<dim3((WR*224 + 255)/256, 14), 256, 0, stream>>>(
      ae_w2, lce_w2, dec_w1, cov_w1, dec_w2, cov_w2, wih, whh, se_w2, ce_w2,
      ae_b2, lce_b2, dec_b1, cov_b1, dec_b2, cov_b2, bhh,
      ae_w1, ae_b1, lce_w1, lce_b1,
      aew2b, lcew2b, decw1b, covw1b, decw2b, covw2b,
      wihab, wihlb, whhb, sew2T, cew2T, wihcT,
      aeb2p, lceb2p, decb1p, covb1p, decb2p, covb2p, bhhp,
      aw1b, lw1b, aeb1p, lceb1p);
  k_zero<<<(CR*24 + BSZ*24 + 255)/256, 256, 0, stream>>>(hidbuf, hcar);

  k_mlp2<<<BSZ, 256, 0, stream>>>(x,    12, se_w1, se_b1, sew2T, se_b2, 1, h0f,   224, hidbuf);
  k_mlp2<<<BSZ, 256, 0, stream>>>(ctxm,  8, ce_w1, ce_b1, cew2T, ce_b2, 0, ctxef, 200, (short*)nullptr);
  k_gictx<<<BSZ, 256, 0, stream>>>(ctxef, wihcT, bih, gic);

  for (int c = 0; c < NCH; ++c){
    k_fuse<<<CR/128, 512, 0, stream>>>(u, lctx, aw1b, aeb1p, lw1b, lceb1p,
                                       aew2b, aeb2p, lcew2b, lceb2p,
                                       wihab, wihlb, gibuf, c*CR);
    k_gru6<<<BSZ/8, 512, 0, stream>>>(gibuf, gic, (c == 0) ? h0f : hcar,
                                      whhb, bhhp, hidbuf, hcar);
    int rowStart = (c == 0) ? 0 : BSZ;
    int nRows    = (c == 0) ? (CT+1)*BSZ : CT*BSZ;
    k_dec<<<nRows/64, 256, 0, stream>>>(hidbuf, rowStart, c*CT*BSZ,
                                        decw1b, decb1p, decw2b, decb2p,
                                        covw1b, covb1p, covw2b, covb2p,
                                        outMean, outStd);
  }
}